// Round 1
// baseline (795.716 us; speedup 1.0000x reference)
//
#include <hip/hip_runtime.h>
#include <hip/hip_bf16.h>

static constexpr int F = 64;       // IN_FT == OUT_FT == 64
static constexpr int TOT = 384;    // 6*F columns in fc_w
static constexpr int KEFF = 320;   // effective K after merging duplicate |y1-y2| block

// One lane per (edge, feature): y[dst] += w * x[src]
__global__ __launch_bounds__(256) void spmm_kernel(
    const float* __restrict__ x, float* __restrict__ y,
    const int* __restrict__ src, const int* __restrict__ dst,
    const float* __restrict__ ew, int ne)
{
    long long t = (long long)blockIdx.x * 256 + threadIdx.x;
    int e = (int)(t >> 6);
    if (e >= ne) return;
    int d = (int)(t & 63);
    int s  = src[e];
    int q  = dst[e];
    float w = ew[e];
    float v = x[(long long)s * F + d] * w;
    atomicAdd(&y[(long long)q * F + d], v);
}

// acc[o4*4 + c] += cv * Wt[k][o4*4 + c]  for all 64 outputs, via float4 LDS reads
#define FMAROW(cv, kk)                                                        \
    {                                                                         \
        const float4* wr = (const float4*)&Wt[(kk) * 64];                     \
        _Pragma("unroll")                                                     \
        for (int o4 = 0; o4 < 16; ++o4) {                                     \
            float4 w = wr[o4];                                                \
            acc[o4 * 4 + 0] += (cv) * w.x;                                    \
            acc[o4 * 4 + 1] += (cv) * w.y;                                    \
            acc[o4 * 4 + 2] += (cv) * w.z;                                    \
            acc[o4 * 4 + 3] += (cv) * w.w;                                    \
        }                                                                     \
    }

// feats = [y4, |y1-y2|, |y2-y4|, |y1-y2|(dup), |y3-y2|, |y4-y3|] @ W^T + bias, PReLU
// W pre-combined so the duplicate block folds into one: KEFF = 320.
__global__ __launch_bounds__(256) void fused_feat_gemm(
    const float* __restrict__ y1, const float* __restrict__ y2,
    const float* __restrict__ y3, const float* __restrict__ y4,
    const float* __restrict__ fcw, const float* __restrict__ bias,
    const float* __restrict__ pa, float* __restrict__ out, int n)
{
    __shared__ float Wt[KEFF * 64];   // [k'][o], 80 KB
    for (int i = threadIdx.x; i < KEFF * 64; i += 256) {
        int k = i >> 6, o = i & 63;
        int j = k & 63;
        float v;
        if (k < 64)       v = fcw[o * TOT + j];                                 // y4
        else if (k < 128) v = fcw[o * TOT + 64 + j] + fcw[o * TOT + 192 + j];   // |y1-y2| (merged)
        else if (k < 192) v = fcw[o * TOT + 128 + j];                           // |y2-y4|
        else if (k < 256) v = fcw[o * TOT + 256 + j];                           // |y3-y2|
        else              v = fcw[o * TOT + 320 + j];                           // |y4-y3|
        Wt[i] = v;
    }
    __syncthreads();

    int node = blockIdx.x * 256 + threadIdx.x;
    if (node >= n) return;

    float acc[64];
#pragma unroll
    for (int o = 0; o < 64; ++o) acc[o] = bias[o];

    const float4* p1 = (const float4*)(y1 + (long long)node * F);
    const float4* p2 = (const float4*)(y2 + (long long)node * F);
    const float4* p3 = (const float4*)(y3 + (long long)node * F);
    const float4* p4 = (const float4*)(y4 + (long long)node * F);

    for (int q = 0; q < 16; ++q) {
        float4 v1 = p1[q], v2 = p2[q], v3 = p3[q], v4 = p4[q];
        float c0[4] = {v4.x, v4.y, v4.z, v4.w};
        float c1[4] = {fabsf(v1.x - v2.x), fabsf(v1.y - v2.y),
                       fabsf(v1.z - v2.z), fabsf(v1.w - v2.w)};
        float c2[4] = {fabsf(v2.x - v4.x), fabsf(v2.y - v4.y),
                       fabsf(v2.z - v4.z), fabsf(v2.w - v4.w)};
        float c3[4] = {fabsf(v3.x - v2.x), fabsf(v3.y - v2.y),
                       fabsf(v3.z - v2.z), fabsf(v3.w - v2.w)};
        float c4[4] = {fabsf(v4.x - v3.x), fabsf(v4.y - v3.y),
                       fabsf(v4.z - v3.z), fabsf(v4.w - v3.w)};
#pragma unroll
        for (int j = 0; j < 4; ++j) {
            int kb = q * 4 + j;
            FMAROW(c0[j], kb);
            FMAROW(c1[j], 64 + kb);
            FMAROW(c2[j], 128 + kb);
            FMAROW(c3[j], 192 + kb);
            FMAROW(c4[j], 256 + kb);
        }
    }

    float a = pa[0];
    float4* po = (float4*)(out + (long long)node * F);
#pragma unroll
    for (int o4 = 0; o4 < 16; ++o4) {
        float4 r;
        float t0 = acc[o4 * 4 + 0], t1 = acc[o4 * 4 + 1];
        float t2 = acc[o4 * 4 + 2], t3 = acc[o4 * 4 + 3];
        r.x = t0 > 0.0f ? t0 : a * t0;
        r.y = t1 > 0.0f ? t1 : a * t1;
        r.z = t2 > 0.0f ? t2 : a * t2;
        r.w = t3 > 0.0f ? t3 : a * t3;
        po[o4] = r;
    }
}

extern "C" void kernel_launch(void* const* d_in, const int* in_sizes, int n_in,
                              void* d_out, int out_size, void* d_ws, size_t ws_size,
                              hipStream_t stream)
{
    const float* seq  = (const float*)d_in[0];
    const int*   eidx = (const int*)d_in[1];
    const float* ew   = (const float*)d_in[2];
    const float* fcw  = (const float*)d_in[3];
    const float* bias = (const float*)d_in[4];
    const float* pa   = (const float*)d_in[5];
    float* out = (float*)d_out;

    int n  = in_sizes[0] / F;     // 50000
    int ne = in_sizes[2];         // 800000
    const int* src = eidx;        // edge_index[0]
    const int* dst = eidx + ne;   // edge_index[1]

    float* y1 = (float*)d_ws;
    float* y2 = y1 + (long long)n * F;
    float* y3 = y2 + (long long)n * F;
    float* y4 = y3 + (long long)n * F;

    // zero all four diffusion buffers (atomics accumulate into them)
    hipMemsetAsync(d_ws, 0, (size_t)4 * (size_t)n * F * sizeof(float), stream);

    long long tt = (long long)ne * F;
    int blocks = (int)((tt + 255) / 256);
    spmm_kernel<<<blocks, 256, 0, stream>>>(seq, y1, src, dst, ew, ne);
    spmm_kernel<<<blocks, 256, 0, stream>>>(y1,  y2, src, dst, ew, ne);
    spmm_kernel<<<blocks, 256, 0, stream>>>(y2,  y3, src, dst, ew, ne);
    spmm_kernel<<<blocks, 256, 0, stream>>>(y3,  y4, src, dst, ew, ne);

    int gblocks = (n + 255) / 256;
    fused_feat_gemm<<<gblocks, 256, 0, stream>>>(y1, y2, y3, y4, fcw, bias, pa, out, n);
}

// Round 2
// 525.108 us; speedup vs baseline: 1.5153x; 1.5153x over previous
//
#include <hip/hip_runtime.h>
#include <hip/hip_bf16.h>

static constexpr int F = 64;       // IN_FT == OUT_FT == 64
static constexpr int TOT = 384;    // 6*F columns in fc_w
static constexpr int KEFF = 320;   // effective K after merging duplicate |y1-y2| block

// ---------------- CSR build (counting sort by dst) ----------------

__global__ __launch_bounds__(256) void hist_kernel(
    const int* __restrict__ dst, int* __restrict__ deg, int ne)
{
    int e = blockIdx.x * 256 + threadIdx.x;
    if (e < ne) atomicAdd(&deg[dst[e]], 1);
}

// single-block exclusive scan over n entries (n ~ 50k)
__global__ __launch_bounds__(1024) void scan_kernel(
    const int* __restrict__ deg, int* __restrict__ rowptr,
    int* __restrict__ cursor, int n)
{
    __shared__ int part[1024];
    int tid = threadIdx.x;
    int chunk = (n + 1023) / 1024;
    int lo = tid * chunk;
    int hi = min(lo + chunk, n);
    int s = 0;
    for (int i = lo; i < hi; ++i) s += deg[i];
    part[tid] = s;
    __syncthreads();
    for (int off = 1; off < 1024; off <<= 1) {
        int v = (tid >= off) ? part[tid - off] : 0;
        __syncthreads();
        part[tid] += v;
        __syncthreads();
    }
    int prefix = (tid == 0) ? 0 : part[tid - 1];
    for (int i = lo; i < hi; ++i) {
        rowptr[i] = prefix;
        cursor[i] = prefix;
        prefix += deg[i];
    }
    if (tid == 1023) rowptr[n] = part[1023];
}

__global__ __launch_bounds__(256) void scatter_kernel(
    const int* __restrict__ src, const int* __restrict__ dst,
    const float* __restrict__ ew, int* __restrict__ cursor,
    int* __restrict__ csr_src, float* __restrict__ csr_w, int ne)
{
    int e = blockIdx.x * 256 + threadIdx.x;
    if (e >= ne) return;
    int d = dst[e];
    int pos = atomicAdd(&cursor[d], 1);
    csr_src[pos] = src[e];
    csr_w[pos]   = ew[e];
}

// ---------------- pull-mode spmm: one wave per node, no atomics ----------------

__global__ __launch_bounds__(256) void spmm_pull(
    const float* __restrict__ x, float* __restrict__ y,
    const int* __restrict__ rowptr, const int* __restrict__ csr_src,
    const float* __restrict__ csr_w, int n)
{
    int wid  = (blockIdx.x * 256 + threadIdx.x) >> 6;  // node
    int lane = threadIdx.x & 63;                       // feature
    if (wid >= n) return;
    int beg = rowptr[wid], end = rowptr[wid + 1];
    float acc = 0.0f;
    int k = beg;
    for (; k + 1 < end; k += 2) {
        int s0 = __builtin_amdgcn_readfirstlane(csr_src[k]);
        int s1 = __builtin_amdgcn_readfirstlane(csr_src[k + 1]);
        float w0 = csr_w[k], w1 = csr_w[k + 1];
        float x0 = x[(long long)s0 * F + lane];
        float x1 = x[(long long)s1 * F + lane];
        acc += w0 * x0;
        acc += w1 * x1;
    }
    if (k < end) {
        int s0 = __builtin_amdgcn_readfirstlane(csr_src[k]);
        acc += csr_w[k] * x[(long long)s0 * F + lane];
    }
    y[(long long)wid * F + lane] = acc;
}

// ---------------- fused feature-build + GEMM + PReLU ----------------
// acc[o4*4+c] += cv * Wt[kk][qbase + o4*4+c] over 16 outputs (4 float4)
#define FMAROW(cv, kk)                                                        \
    {                                                                         \
        const float4* wr = (const float4*)&Wt[(kk) * 64 + qbase];             \
        _Pragma("unroll")                                                     \
        for (int o4 = 0; o4 < 4; ++o4) {                                      \
            float4 w = wr[o4];                                                \
            acc[o4 * 4 + 0] += (cv) * w.x;                                    \
            acc[o4 * 4 + 1] += (cv) * w.y;                                    \
            acc[o4 * 4 + 2] += (cv) * w.z;                                    \
            acc[o4 * 4 + 3] += (cv) * w.w;                                    \
        }                                                                     \
    }

// feats = [y4, |y1-y2|, |y2-y4|, |y1-y2|(dup), |y3-y2|, |y4-y3|] @ W^T + bias, PReLU
// W pre-combined so the duplicate block folds in: KEFF = 320.
// 4 threads per node, 16 outputs each -> 4x occupancy vs 1 thread/node.
__global__ __launch_bounds__(256) void fused_feat_gemm(
    const float* __restrict__ y1, const float* __restrict__ y2,
    const float* __restrict__ y3, const float* __restrict__ y4,
    const float* __restrict__ fcw, const float* __restrict__ bias,
    const float* __restrict__ pa, float* __restrict__ out, int n)
{
    __shared__ float Wt[KEFF * 64];   // [k'][o], 80 KB
    for (int i = threadIdx.x; i < KEFF * 64; i += 256) {
        int k = i >> 6, o = i & 63;
        int j = k & 63;
        float v;
        if (k < 64)       v = fcw[o * TOT + j];                                 // y4
        else if (k < 128) v = fcw[o * TOT + 64 + j] + fcw[o * TOT + 192 + j];   // |y1-y2| merged
        else if (k < 192) v = fcw[o * TOT + 128 + j];                           // |y2-y4|
        else if (k < 256) v = fcw[o * TOT + 256 + j];                           // |y3-y2|
        else              v = fcw[o * TOT + 320 + j];                           // |y4-y3|
        Wt[i] = v;
    }
    __syncthreads();

    int gid  = blockIdx.x * 256 + threadIdx.x;
    int node = gid >> 2;
    int q    = gid & 3;          // output quarter
    int qbase = q * 16;
    if (node >= n) return;

    float acc[16];
#pragma unroll
    for (int o = 0; o < 16; ++o) acc[o] = bias[qbase + o];

    const float4* p1 = (const float4*)(y1 + (long long)node * F);
    const float4* p2 = (const float4*)(y2 + (long long)node * F);
    const float4* p3 = (const float4*)(y3 + (long long)node * F);
    const float4* p4 = (const float4*)(y4 + (long long)node * F);

    for (int t = 0; t < 16; ++t) {
        float4 v1 = p1[t], v2 = p2[t], v3 = p3[t], v4 = p4[t];
        float c0[4] = {v4.x, v4.y, v4.z, v4.w};
        float c1[4] = {fabsf(v1.x - v2.x), fabsf(v1.y - v2.y),
                       fabsf(v1.z - v2.z), fabsf(v1.w - v2.w)};
        float c2[4] = {fabsf(v2.x - v4.x), fabsf(v2.y - v4.y),
                       fabsf(v2.z - v4.z), fabsf(v2.w - v4.w)};
        float c3[4] = {fabsf(v3.x - v2.x), fabsf(v3.y - v2.y),
                       fabsf(v3.z - v2.z), fabsf(v3.w - v2.w)};
        float c4[4] = {fabsf(v4.x - v3.x), fabsf(v4.y - v3.y),
                       fabsf(v4.z - v3.z), fabsf(v4.w - v3.w)};
#pragma unroll
        for (int j = 0; j < 4; ++j) {
            int kb = t * 4 + j;
            FMAROW(c0[j], kb);
            FMAROW(c1[j], 64 + kb);
            FMAROW(c2[j], 128 + kb);
            FMAROW(c3[j], 192 + kb);
            FMAROW(c4[j], 256 + kb);
        }
    }

    float a = pa[0];
    float4* po = (float4*)(out + (long long)node * F + qbase);
#pragma unroll
    for (int o4 = 0; o4 < 4; ++o4) {
        float4 r;
        float t0 = acc[o4 * 4 + 0], t1 = acc[o4 * 4 + 1];
        float t2 = acc[o4 * 4 + 2], t3 = acc[o4 * 4 + 3];
        r.x = t0 > 0.0f ? t0 : a * t0;
        r.y = t1 > 0.0f ? t1 : a * t1;
        r.z = t2 > 0.0f ? t2 : a * t2;
        r.w = t3 > 0.0f ? t3 : a * t3;
        po[o4] = r;
    }
}

extern "C" void kernel_launch(void* const* d_in, const int* in_sizes, int n_in,
                              void* d_out, int out_size, void* d_ws, size_t ws_size,
                              hipStream_t stream)
{
    const float* seq  = (const float*)d_in[0];
    const int*   eidx = (const int*)d_in[1];
    const float* ew   = (const float*)d_in[2];
    const float* fcw  = (const float*)d_in[3];
    const float* bias = (const float*)d_in[4];
    const float* pa   = (const float*)d_in[5];
    float* out = (float*)d_out;

    int n  = in_sizes[0] / F;     // 50000
    int ne = in_sizes[2];         // 800000
    const int* src = eidx;        // edge_index[0]
    const int* dst = eidx + ne;   // edge_index[1]

    // workspace layout (all 4-byte elems): ~58.2 MB
    float* y1      = (float*)d_ws;
    float* y2      = y1 + (long long)n * F;
    float* y3      = y2 + (long long)n * F;
    float* y4      = y3 + (long long)n * F;
    float* csr_w   = y4 + (long long)n * F;
    int*   csr_src = (int*)(csr_w + ne);
    int*   rowptr  = csr_src + ne;
    int*   cursor  = rowptr + (n + 1);
    int*   deg     = cursor + n;

    hipMemsetAsync(deg, 0, (size_t)n * sizeof(int), stream);

    int eb = (ne + 255) / 256;
    hist_kernel<<<eb, 256, 0, stream>>>(dst, deg, ne);
    scan_kernel<<<1, 1024, 0, stream>>>(deg, rowptr, cursor, n);
    scatter_kernel<<<eb, 256, 0, stream>>>(src, dst, ew, cursor, csr_src, csr_w, ne);

    int sb = ((long long)n * 64 + 255) / 256;
    spmm_pull<<<sb, 256, 0, stream>>>(seq, y1, rowptr, csr_src, csr_w, n);
    spmm_pull<<<sb, 256, 0, stream>>>(y1,  y2, rowptr, csr_src, csr_w, n);
    spmm_pull<<<sb, 256, 0, stream>>>(y2,  y3, rowptr, csr_src, csr_w, n);
    spmm_pull<<<sb, 256, 0, stream>>>(y3,  y4, rowptr, csr_src, csr_w, n);

    int gb = ((long long)n * 4 + 255) / 256;
    fused_feat_gemm<<<gb, 256, 0, stream>>>(y1, y2, y3, y4, fcw, bias, pa, out, n);
}